// Round 20
// baseline (247.039 us; speedup 1.0000x reference)
//
#include <hip/hip_runtime.h>
#include <math.h>

// Problem constants (b=8, c=2048, e=64, h=8)
#define NTOK 16384
#define EDIM 64
#define HHE  512   // h*e
#define TOKPAD 260 // half2 slots per token row: 256 + 4 pad (16B-aligned rows)

typedef _Float16 half8 __attribute__((ext_vector_type(8)));   // MFMA operand type
typedef __fp16   half2v __attribute__((ext_vector_type(2)));  // builtin V2h type
typedef float    floatx4 __attribute__((ext_vector_type(4)));

__device__ __forceinline__ half8 cvt8(const float4 a, const float4 b) {
    half8 h;
    h[0] = (_Float16)a.x; h[1] = (_Float16)a.y;
    h[2] = (_Float16)a.z; h[3] = (_Float16)a.w;
    h[4] = (_Float16)b.x; h[5] = (_Float16)b.y;
    h[6] = (_Float16)b.z; h[7] = (_Float16)b.w;
    return h;
}

// fp32 += half2 . half2 (v_dot2_f32_f16); float fallback if builtin missing
__device__ __forceinline__ float dot2(half2v a, half2v b, float c) {
#if __has_builtin(__builtin_amdgcn_fdot2)
    return __builtin_amdgcn_fdot2(a, b, c, false);
#else
    return fmaf((float)a[0], (float)b[0], fmaf((float)a[1], (float)b[1], c));
#endif
}
__device__ __forceinline__ half2v pk(float x, float y) {
    return __builtin_amdgcn_cvt_pkrtz(x, y);   // v_cvt_pkrtz_f16_f32 (V2h)
}
union h2u { half2v h; unsigned int u; };

__device__ __forceinline__ float clamp01(float z) {
    return __builtin_amdgcn_fmed3f(z, 0.0f, 1.0f);   // v_med3_f32
}
__device__ __forceinline__ float pgen(float z, float inv) {
    return z > 0.0f ? exp2f(inv * log2f(fmaxf(z, 1e-30f))) : 0.0f;
}

// ---------------------------------------------------------------------------
// Kernel 0: one-shot fp32 -> fp16 (RTN cast) for x + all W. (R16, unchanged)
// ---------------------------------------------------------------------------
__global__ __launch_bounds__(256) void cvt_fp16_kernel(
    const float* __restrict__ x,
    const float* __restrict__ Wk, const float* __restrict__ Wq,
    const float* __restrict__ Wv, const float* __restrict__ Wu,
    __fp16* __restrict__ xh, __fp16* __restrict__ wkh,
    __fp16* __restrict__ wqh, __fp16* __restrict__ wvh,
    __fp16* __restrict__ wuh)
{
    const int z = blockIdx.y;
    const float* src; __fp16* dst; int n;
    if      (z == 0) { src = x;  dst = xh;  n = NTOK * EDIM; }
    else if (z == 1) { src = Wk; dst = wkh; n = HHE * EDIM; }
    else if (z == 2) { src = Wq; dst = wqh; n = HHE * EDIM; }
    else if (z == 3) { src = Wv; dst = wvh; n = HHE * EDIM; }
    else             { src = Wu; dst = wuh; n = EDIM * HHE; }
    const int idx = (blockIdx.x * 256 + threadIdx.x) * 8;
    if (idx < n) {
        const float4 a = *(const float4*)(src + idx);
        const float4 b = *(const float4*)(src + idx + 4);
        *(half8*)(dst + idx) = cvt8(a, b);
    }
}

// ---------------------------------------------------------------------------
// Kernel 1: FULLY FUSED qkv + entmax-attention + out projection.
// R20 change: 8 WAVES (512 threads) per 16-token block, same 50 KB LDS ->
// 3 blocks/CU still fit by LDS but waves/CU doubles 12 -> 24 (VGPR 84 <=
// 85 = 512/6 so 6 waves/SIMD fit). Consumer: 2 tokens/wave (was 4);
// producer: 12 units as waves 0-3 x2 + waves 4-7 x1; out: waves 0-3 take
// the 4 col-tiles. All arithmetic/layouts byte-identical to R19.
// ---------------------------------------------------------------------------
__global__ __launch_bounds__(512, 5) void qkv_attn_out_kernel(
    const __fp16* __restrict__ xh,
    const __fp16* __restrict__ wkh, const float* __restrict__ bk,
    const __fp16* __restrict__ wqh, const float* __restrict__ bq,
    const __fp16* __restrict__ wvh, const float* __restrict__ bv,
    const __fp16* __restrict__ wuh, const float* __restrict__ bu,
    float* __restrict__ out, const float* alpha_p)
{
    __shared__ __align__(16) half2v qT[16 * TOKPAD];  // [tok][i*4+hpair] -> res overlay
    __shared__ __align__(16) half2v kT[16 * TOKPAD];  // [tok][j*4 + hpair]
    __shared__ __align__(16) half2v vT[16 * TOKPAD];  // [tok][h*32 + jpair]

    const int tid  = threadIdx.x;
    const int lane = tid & 63;
    const int w    = tid >> 6;             // wave 0..7
    const int tok0 = blockIdx.x * 16;

    const int m    = lane & 15;            // token (B row)
    const int quad = lane >> 4;

    // ---- x B-fragments (direct fp16), shared by this wave's units
    const __fp16* xrow = xh + (size_t)(tok0 + m) * EDIM + quad * 8;
    half8 bfr[2];
    bfr[0] = *(const half8*)(xrow);
    bfr[1] = *(const half8*)(xrow + 32);

    // ---- producer: unit = w (all waves) and w+8 (waves 0..3)
    #pragma unroll
    for (int uu = 0; uu < 2; ++uu) {
        const int unit = w + uu * 8;
        if (unit < 12) {
            const int z    = unit >> 2;            // 0=k, 1=q, 2=v
            const int col0 = (unit & 3) * 128;
            const __fp16* W   = (z == 0) ? wkh : (z == 1) ? wqh : wvh;
            const float* bias = (z == 0) ? bk : (z == 1) ? bq : bv;
            half2v* dstT      = (z == 0) ? kT : (z == 1) ? qT : vT;

            #pragma unroll
            for (int ct = 0; ct < 8; ++ct) {
                const int n = col0 + ct * 16 + m;
                // permuted W row for q/k; natural for v
                const int grow = (z < 2) ? ((n & 7) * 64 + (n >> 3)) : n;
                const __fp16* wrow = W + (size_t)grow * EDIM + quad * 8;
                floatx4 acc = (floatx4){0.f, 0.f, 0.f, 0.f};
                #pragma unroll
                for (int kc = 0; kc < 2; ++kc) {
                    const half8 af = *(const half8*)(wrow + kc * 32);
                    acc = __builtin_amdgcn_mfma_f32_16x16x32_f16(af, bfr[kc], acc, 0, 0, 0);
                }
                // lane's 4 regs = D rows quad*4+0..3, D col = m (token)
                h2u p0, p1;
                if (z < 2) {
                    // rows g(n'): h = 4*(quad&1)+reg, j = col0/8+ct*2+(quad>>1)
                    const int hbase = 4 * (quad & 1);
                    const int j     = (col0 >> 3) + ct * 2 + (quad >> 1);
                    float o0 = acc[0] + bias[(hbase + 0) * 64 + j];
                    float o1 = acc[1] + bias[(hbase + 1) * 64 + j];
                    float o2 = acc[2] + bias[(hbase + 2) * 64 + j];
                    float o3 = acc[3] + bias[(hbase + 3) * 64 + j];
                    p0.h = pk(o0, o1);                 // h-pair 2*(quad&1)
                    p1.h = pk(o2, o3);                 // h-pair 2*(quad&1)+1
                    uint2 st; st.x = p0.u; st.y = p1.u;
                    *(uint2*)&dstT[m * TOKPAD + j * 4 + 2 * (quad & 1)] = st;
                } else {
                    // natural: cols nn..nn+3 = v[h][jj..jj+3]
                    const int nn = col0 + ct * 16 + quad * 4;
                    const int h  = nn >> 6;
                    const int jj = nn & 63;
                    const float4 b4 = *(const float4*)&bias[nn];
                    p0.h = pk(acc[0] + b4.x, acc[1] + b4.y);
                    p1.h = pk(acc[2] + b4.z, acc[3] + b4.w);
                    uint2 st; st.x = p0.u; st.y = p1.u;
                    *(uint2*)&dstT[m * TOKPAD + h * 32 + (jj >> 1)] = st;
                }
            }
        }
    }
    __syncthreads();   // producer (all 16 tokens staged) -> consumer

    const float alpha = alpha_p[0];
    const float am1   = alpha - 1.0f;
    __fp16* resL = (__fp16*)qT;            // res overlay: row stride 520 halves

    // ---- consumer: each wave runs 2 tokens serially
    for (int i = 0; i < 2; ++i) {
        const int t = w * 2 + i;

        union { half8 h8; half2v h2[4]; } uq;
        uq.h8 = *(const half8*)&qT[t * TOKPAD + lane * 4];  // qT row t dead after this

        // dot row: row[j] = sum_h q[h][lane] * k[h][j]  (4 dot2 per j)
        float row[64];
        #pragma unroll
        for (int j = 0; j < 64; ++j) {
            union { half8 h8; half2v h2[4]; } u;
            u.h8 = *(const half8*)&kT[t * TOKPAD + j * 4];   // broadcast b128
            float d = dot2(uq.h2[0], u.h2[0], 0.0f);
            d = dot2(uq.h2[1], u.h2[1], d);
            d = dot2(uq.h2[2], u.h2[2], d);
            d = dot2(uq.h2[3], u.h2[3], d);
            row[j] = d;
        }

        // Xa = dot/sqrt(e) * (alpha-1);  1/8 and am1 fold exactly (pow-of-2)
        const float scale = am1 * 0.125f;
        #pragma unroll
        for (int j = 0; j < 64; ++j) row[j] *= scale;

        float mx = row[0];
        #pragma unroll
        for (int j = 1; j < 64; ++j) mx = fmaxf(mx, row[j]);

        float tau_lo = mx - 1.0f;                         // _gp(1, alpha) = 1
        const float tau_hi = mx - exp2f(-6.0f * am1);     // (1/64)^am1
        float dm = tau_hi - tau_lo;
        float inv_sum;

        if (am1 == 0.5f) {
            // 6 bisection steps, f >= 0 test (f_lo >= 0 provably; one-hot-safe)
            #pragma unroll
            for (int it = 0; it < 6; ++it) {
                dm *= 0.5f;
                const float tau_m = tau_lo + dm;
                float f0 = -1.0f, f1 = 0.0f, f2 = 0.0f, f3 = 0.0f;
                #pragma unroll
                for (int j = 0; j < 64; j += 4) {
                    const float a0 = clamp01(row[j+0] - tau_m);
                    const float a1 = clamp01(row[j+1] - tau_m);
                    const float a2 = clamp01(row[j+2] - tau_m);
                    const float a3 = clamp01(row[j+3] - tau_m);
                    f0 = fmaf(a0, a0, f0); f1 = fmaf(a1, a1, f1);
                    f2 = fmaf(a2, a2, f2); f3 = fmaf(a3, a3, f3);
                }
                const float f = (f0 + f1) + (f2 + f3);
                tau_lo = (f >= 0.0f) ? tau_m : tau_lo;
            }
            // 2 guarded Newton steps (tau += max(f,0)/(2s); never moves if f<0)
            float tau = tau_lo;
            #pragma unroll
            for (int it = 0; it < 2; ++it) {
                float f0 = -1.0f, f1 = 0.0f, f2 = 0.0f, f3 = 0.0f;
                float s0 = 0.0f, s1 = 0.0f, s2 = 0.0f, s3 = 0.0f;
                #pragma unroll
                for (int j = 0; j < 64; j += 4) {
                    const float a0 = clamp01(row[j+0] - tau);
                    const float a1 = clamp01(row[j+1] - tau);
                    const float a2 = clamp01(row[j+2] - tau);
                    const float a3 = clamp01(row[j+3] - tau);
                    f0 = fmaf(a0, a0, f0); f1 = fmaf(a1, a1, f1);
                    f2 = fmaf(a2, a2, f2); f3 = fmaf(a3, a3, f3);
                    s0 += a0; s1 += a1; s2 += a2; s3 += a3;
                }
                const float f = (f0 + f1) + (f2 + f3);
                const float s = ((s0 + s1) + (s2 + s3)) + 1e-20f;  // s >= 1/8
                tau = tau + fmaxf(f, 0.0f) / (s + s);
            }
            // final p (unnormalized) + sum; normalization folded into av
            float s0 = 0.0f, s1 = 0.0f;
            #pragma unroll
            for (int j = 0; j < 64; j += 2) {
                float a0 = clamp01(row[j+0] - tau);
                float a1 = clamp01(row[j+1] - tau);
                a0 *= a0; a1 *= a1;
                row[j+0] = a0; row[j+1] = a1;
                s0 += a0; s1 += a1;
            }
            inv_sum = 1.0f / (s0 + s1);
        } else {
            // faithful general-alpha path (unused for this problem's alpha=1.5)
            const float inv = 1.0f / am1;
            float tau_m = tau_lo;
            float f_lo = -1.0f;
            #pragma unroll
            for (int j = 0; j < 64; ++j) f_lo += pgen(row[j] - tau_lo, inv);
            for (int it = 0; it < 30; ++it) {
                dm *= 0.5f;
                tau_m = tau_lo + dm;
                float f = -1.0f;
                #pragma unroll
                for (int j = 0; j < 64; ++j) f += pgen(row[j] - tau_m, inv);
                tau_lo = (f * f_lo >= 0.0f) ? tau_m : tau_lo;
            }
            float s = 0.0f;
            #pragma unroll
            for (int j = 0; j < 64; ++j) {
                const float pm = pgen(row[j] - tau_m, inv);
                row[j] = pm;
                s += pm;
            }
            inv_sum = 1.0f / s;
        }

        // av: res[h][lane] = inv_sum * sum_j p[j] * v[h][j]  via fp16 dot2
        half2v p2[32];
        #pragma unroll
        for (int ii = 0; ii < 32; ++ii) p2[ii] = pk(row[2 * ii], row[2 * ii + 1]);

        float acc[8];
        #pragma unroll
        for (int h = 0; h < 8; ++h) {
            float a0 = 0.0f, a1 = 0.0f;
            #pragma unroll
            for (int jc = 0; jc < 8; ++jc) {
                union { half8 h8; half2v h2[4]; } u;
                u.h8 = *(const half8*)&vT[t * TOKPAD + h * 32 + jc * 4];
                a0 = dot2(p2[jc * 4 + 0], u.h2[0], a0);
                a1 = dot2(p2[jc * 4 + 1], u.h2[1], a1);
                a0 = dot2(p2[jc * 4 + 2], u.h2[2], a0);
                a1 = dot2(p2[jc * 4 + 3], u.h2[3], a1);
            }
            acc[h] = a0 + a1;
        }
        // res -> LDS overlay of qT row t (wave-private row; same fp16 cast)
        #pragma unroll
        for (int h = 0; h < 8; ++h)
            resL[t * 520 + h * 64 + lane] = (__fp16)(acc[h] * inv_sum);
    }
    __syncthreads();   // all 16 tokens' res in LDS -> out phase

    // ---- out phase: waves 0-3 compute out col tiles w*16..w*16+15.
    if (w < 4) {
        floatx4 oacc = (floatx4){0.f, 0.f, 0.f, 0.f};
        const __fp16* rrow = resL + (size_t)m * 520 + quad * 8;   // token m
        const __fp16* wrow = wuh + (size_t)(w * 16 + m) * HHE + quad * 8;
        #pragma unroll
        for (int kc = 0; kc < 16; ++kc) {              // K=512 in 32-chunks
            const half8 bf = *(const half8*)(rrow + kc * 32);
            const half8 af = *(const half8*)(wrow + kc * 32);
            oacc = __builtin_amdgcn_mfma_f32_16x16x32_f16(af, bf, oacc, 0, 0, 0);
        }
        const int tok = tok0 + m;
        const int col = w * 16 + quad * 4;             // 4 consecutive out cols
        const float4 b4 = *(const float4*)&bu[col];
        float4 o;
        o.x = oacc[0] + b4.x;
        o.y = oacc[1] + b4.y;
        o.z = oacc[2] + b4.z;
        o.w = oacc[3] + b4.w;
        *(float4*)&out[(size_t)tok * 64 + col] = o;
    }
}

// ---------------------------------------------------------------------------
extern "C" void kernel_launch(void* const* d_in, const int* in_sizes, int n_in,
                              void* d_out, int out_size, void* d_ws, size_t ws_size,
                              hipStream_t stream)
{
    const float* x     = (const float*)d_in[0];
    const float* alpha = (const float*)d_in[1];
    const float* Wk    = (const float*)d_in[2];
    const float* bk    = (const float*)d_in[3];
    const float* Wq    = (const float*)d_in[4];
    const float* bq    = (const float*)d_in[5];
    const float* Wv    = (const float*)d_in[6];
    const float* bv    = (const float*)d_in[7];
    const float* Wu    = (const float*)d_in[8];
    const float* bu    = (const float*)d_in[9];
    float* out = (float*)d_out;

    // workspace (fp16 units): xh 1M | wkh/wqh/wvh/wuh 32768 each
    __fp16* xh   = (__fp16*)d_ws;
    __fp16* wkh  = xh  + (size_t)NTOK * EDIM;
    __fp16* wqh  = wkh + (size_t)HHE * EDIM;
    __fp16* wvh  = wqh + (size_t)HHE * EDIM;
    __fp16* wuh  = wvh + (size_t)HHE * EDIM;

    cvt_fp16_kernel<<<dim3(512, 5), 256, 0, stream>>>(
        x, Wk, Wq, Wv, Wu, xh, wkh, wqh, wvh, wuh);
    qkv_attn_out_kernel<<<NTOK / 16, 512, 0, stream>>>(
        xh, wkh, bk, wqh, bq, wvh, bv, wuh, bu, out, alpha);
}

// Round 21
// 172.420 us; speedup vs baseline: 1.4328x; 1.4328x over previous
//
#include <hip/hip_runtime.h>
#include <math.h>

// Problem constants (b=8, c=2048, e=64, h=8)
#define NTOK 16384
#define EDIM 64
#define HHE  512   // h*e
#define TOKPAD 260 // half2 slots per token row: 256 + 4 pad (16B-aligned rows)

typedef _Float16 half8 __attribute__((ext_vector_type(8)));   // MFMA operand type
typedef __fp16   half2v __attribute__((ext_vector_type(2)));  // builtin V2h type
typedef float    floatx4 __attribute__((ext_vector_type(4)));

__device__ __forceinline__ half8 cvt8(const float4 a, const float4 b) {
    half8 h;
    h[0] = (_Float16)a.x; h[1] = (_Float16)a.y;
    h[2] = (_Float16)a.z; h[3] = (_Float16)a.w;
    h[4] = (_Float16)b.x; h[5] = (_Float16)b.y;
    h[6] = (_Float16)b.z; h[7] = (_Float16)b.w;
    return h;
}

// fp32 += half2 . half2 (v_dot2_f32_f16); float fallback if builtin missing
__device__ __forceinline__ float dot2(half2v a, half2v b, float c) {
#if __has_builtin(__builtin_amdgcn_fdot2)
    return __builtin_amdgcn_fdot2(a, b, c, false);
#else
    return fmaf((float)a[0], (float)b[0], fmaf((float)a[1], (float)b[1], c));
#endif
}
__device__ __forceinline__ half2v pk(float x, float y) {
    return __builtin_amdgcn_cvt_pkrtz(x, y);   // v_cvt_pkrtz_f16_f32 (V2h)
}
union h2u { half2v h; unsigned int u; };

__device__ __forceinline__ float clamp01(float z) {
    return __builtin_amdgcn_fmed3f(z, 0.0f, 1.0f);   // v_med3_f32
}
__device__ __forceinline__ float pgen(float z, float inv) {
    return z > 0.0f ? exp2f(inv * log2f(fmaxf(z, 1e-30f))) : 0.0f;
}

// ---------------------------------------------------------------------------
// Kernel 0: one-shot fp32 -> fp16 (RTN cast) for x + all W. (R16, unchanged)
// ---------------------------------------------------------------------------
__global__ __launch_bounds__(256) void cvt_fp16_kernel(
    const float* __restrict__ x,
    const float* __restrict__ Wk, const float* __restrict__ Wq,
    const float* __restrict__ Wv, const float* __restrict__ Wu,
    __fp16* __restrict__ xh, __fp16* __restrict__ wkh,
    __fp16* __restrict__ wqh, __fp16* __restrict__ wvh,
    __fp16* __restrict__ wuh)
{
    const int z = blockIdx.y;
    const float* src; __fp16* dst; int n;
    if      (z == 0) { src = x;  dst = xh;  n = NTOK * EDIM; }
    else if (z == 1) { src = Wk; dst = wkh; n = HHE * EDIM; }
    else if (z == 2) { src = Wq; dst = wqh; n = HHE * EDIM; }
    else if (z == 3) { src = Wv; dst = wvh; n = HHE * EDIM; }
    else             { src = Wu; dst = wuh; n = EDIM * HHE; }
    const int idx = (blockIdx.x * 256 + threadIdx.x) * 8;
    if (idx < n) {
        const float4 a = *(const float4*)(src + idx);
        const float4 b = *(const float4*)(src + idx + 4);
        *(half8*)(dst + idx) = cvt8(a, b);
    }
}

// ---------------------------------------------------------------------------
// Kernel 1: FULLY FUSED qkv + entmax-attention + out projection.
// R21 = R20's 8-wave mapping with the launch bound FIXED: (512, 3) caps
// VGPR at ~170, not 48. R20's (512,5) forced VGPR=48 -> row[64] spilled to
// scratch (270 MB writes, 155 MB fetches, 2.4 TB/s of spill traffic) and
// never tested the occupancy hypothesis. At the natural ~84 VGPR: 6
// waves/SIMD fit -> 3 blocks/CU = 24 waves/CU (vs R19's 12).
// All arithmetic/layouts byte-identical to R19.
// ---------------------------------------------------------------------------
__global__ __launch_bounds__(512, 3) void qkv_attn_out_kernel(
    const __fp16* __restrict__ xh,
    const __fp16* __restrict__ wkh, const float* __restrict__ bk,
    const __fp16* __restrict__ wqh, const float* __restrict__ bq,
    const __fp16* __restrict__ wvh, const float* __restrict__ bv,
    const __fp16* __restrict__ wuh, const float* __restrict__ bu,
    float* __restrict__ out, const float* alpha_p)
{
    __shared__ __align__(16) half2v qT[16 * TOKPAD];  // [tok][i*4+hpair] -> res overlay
    __shared__ __align__(16) half2v kT[16 * TOKPAD];  // [tok][j*4 + hpair]
    __shared__ __align__(16) half2v vT[16 * TOKPAD];  // [tok][h*32 + jpair]

    const int tid  = threadIdx.x;
    const int lane = tid & 63;
    const int w    = tid >> 6;             // wave 0..7
    const int tok0 = blockIdx.x * 16;

    const int m    = lane & 15;            // token (B row)
    const int quad = lane >> 4;

    // ---- x B-fragments (direct fp16), shared by this wave's units
    const __fp16* xrow = xh + (size_t)(tok0 + m) * EDIM + quad * 8;
    half8 bfr[2];
    bfr[0] = *(const half8*)(xrow);
    bfr[1] = *(const half8*)(xrow + 32);

    // ---- producer: unit = w (all waves) and w+8 (waves 0..3)
    #pragma unroll
    for (int uu = 0; uu < 2; ++uu) {
        const int unit = w + uu * 8;
        if (unit < 12) {
            const int z    = unit >> 2;            // 0=k, 1=q, 2=v
            const int col0 = (unit & 3) * 128;
            const __fp16* W   = (z == 0) ? wkh : (z == 1) ? wqh : wvh;
            const float* bias = (z == 0) ? bk : (z == 1) ? bq : bv;
            half2v* dstT      = (z == 0) ? kT : (z == 1) ? qT : vT;

            #pragma unroll
            for (int ct = 0; ct < 8; ++ct) {
                const int n = col0 + ct * 16 + m;
                // permuted W row for q/k; natural for v
                const int grow = (z < 2) ? ((n & 7) * 64 + (n >> 3)) : n;
                const __fp16* wrow = W + (size_t)grow * EDIM + quad * 8;
                floatx4 acc = (floatx4){0.f, 0.f, 0.f, 0.f};
                #pragma unroll
                for (int kc = 0; kc < 2; ++kc) {
                    const half8 af = *(const half8*)(wrow + kc * 32);
                    acc = __builtin_amdgcn_mfma_f32_16x16x32_f16(af, bfr[kc], acc, 0, 0, 0);
                }
                // lane's 4 regs = D rows quad*4+0..3, D col = m (token)
                h2u p0, p1;
                if (z < 2) {
                    // rows g(n'): h = 4*(quad&1)+reg, j = col0/8+ct*2+(quad>>1)
                    const int hbase = 4 * (quad & 1);
                    const int j     = (col0 >> 3) + ct * 2 + (quad >> 1);
                    float o0 = acc[0] + bias[(hbase + 0) * 64 + j];
                    float o1 = acc[1] + bias[(hbase + 1) * 64 + j];
                    float o2 = acc[2] + bias[(hbase + 2) * 64 + j];
                    float o3 = acc[3] + bias[(hbase + 3) * 64 + j];
                    p0.h = pk(o0, o1);                 // h-pair 2*(quad&1)
                    p1.h = pk(o2, o3);                 // h-pair 2*(quad&1)+1
                    uint2 st; st.x = p0.u; st.y = p1.u;
                    *(uint2*)&dstT[m * TOKPAD + j * 4 + 2 * (quad & 1)] = st;
                } else {
                    // natural: cols nn..nn+3 = v[h][jj..jj+3]
                    const int nn = col0 + ct * 16 + quad * 4;
                    const int h  = nn >> 6;
                    const int jj = nn & 63;
                    const float4 b4 = *(const float4*)&bias[nn];
                    p0.h = pk(acc[0] + b4.x, acc[1] + b4.y);
                    p1.h = pk(acc[2] + b4.z, acc[3] + b4.w);
                    uint2 st; st.x = p0.u; st.y = p1.u;
                    *(uint2*)&dstT[m * TOKPAD + h * 32 + (jj >> 1)] = st;
                }
            }
        }
    }
    __syncthreads();   // producer (all 16 tokens staged) -> consumer

    const float alpha = alpha_p[0];
    const float am1   = alpha - 1.0f;
    __fp16* resL = (__fp16*)qT;            // res overlay: row stride 520 halves

    // ---- consumer: each wave runs 2 tokens serially
    for (int i = 0; i < 2; ++i) {
        const int t = w * 2 + i;

        union { half8 h8; half2v h2[4]; } uq;
        uq.h8 = *(const half8*)&qT[t * TOKPAD + lane * 4];  // qT row t dead after this

        // dot row: row[j] = sum_h q[h][lane] * k[h][j]  (4 dot2 per j)
        float row[64];
        #pragma unroll
        for (int j = 0; j < 64; ++j) {
            union { half8 h8; half2v h2[4]; } u;
            u.h8 = *(const half8*)&kT[t * TOKPAD + j * 4];   // broadcast b128
            float d = dot2(uq.h2[0], u.h2[0], 0.0f);
            d = dot2(uq.h2[1], u.h2[1], d);
            d = dot2(uq.h2[2], u.h2[2], d);
            d = dot2(uq.h2[3], u.h2[3], d);
            row[j] = d;
        }

        // Xa = dot/sqrt(e) * (alpha-1);  1/8 and am1 fold exactly (pow-of-2)
        const float scale = am1 * 0.125f;
        #pragma unroll
        for (int j = 0; j < 64; ++j) row[j] *= scale;

        float mx = row[0];
        #pragma unroll
        for (int j = 1; j < 64; ++j) mx = fmaxf(mx, row[j]);

        float tau_lo = mx - 1.0f;                         // _gp(1, alpha) = 1
        const float tau_hi = mx - exp2f(-6.0f * am1);     // (1/64)^am1
        float dm = tau_hi - tau_lo;
        float inv_sum;

        if (am1 == 0.5f) {
            // 6 bisection steps, f >= 0 test (f_lo >= 0 provably; one-hot-safe)
            #pragma unroll
            for (int it = 0; it < 6; ++it) {
                dm *= 0.5f;
                const float tau_m = tau_lo + dm;
                float f0 = -1.0f, f1 = 0.0f, f2 = 0.0f, f3 = 0.0f;
                #pragma unroll
                for (int j = 0; j < 64; j += 4) {
                    const float a0 = clamp01(row[j+0] - tau_m);
                    const float a1 = clamp01(row[j+1] - tau_m);
                    const float a2 = clamp01(row[j+2] - tau_m);
                    const float a3 = clamp01(row[j+3] - tau_m);
                    f0 = fmaf(a0, a0, f0); f1 = fmaf(a1, a1, f1);
                    f2 = fmaf(a2, a2, f2); f3 = fmaf(a3, a3, f3);
                }
                const float f = (f0 + f1) + (f2 + f3);
                tau_lo = (f >= 0.0f) ? tau_m : tau_lo;
            }
            // 2 guarded Newton steps (tau += max(f,0)/(2s); never moves if f<0)
            float tau = tau_lo;
            #pragma unroll
            for (int it = 0; it < 2; ++it) {
                float f0 = -1.0f, f1 = 0.0f, f2 = 0.0f, f3 = 0.0f;
                float s0 = 0.0f, s1 = 0.0f, s2 = 0.0f, s3 = 0.0f;
                #pragma unroll
                for (int j = 0; j < 64; j += 4) {
                    const float a0 = clamp01(row[j+0] - tau);
                    const float a1 = clamp01(row[j+1] - tau);
                    const float a2 = clamp01(row[j+2] - tau);
                    const float a3 = clamp01(row[j+3] - tau);
                    f0 = fmaf(a0, a0, f0); f1 = fmaf(a1, a1, f1);
                    f2 = fmaf(a2, a2, f2); f3 = fmaf(a3, a3, f3);
                    s0 += a0; s1 += a1; s2 += a2; s3 += a3;
                }
                const float f = (f0 + f1) + (f2 + f3);
                const float s = ((s0 + s1) + (s2 + s3)) + 1e-20f;  // s >= 1/8
                tau = tau + fmaxf(f, 0.0f) / (s + s);
            }
            // final p (unnormalized) + sum; normalization folded into av
            float s0 = 0.0f, s1 = 0.0f;
            #pragma unroll
            for (int j = 0; j < 64; j += 2) {
                float a0 = clamp01(row[j+0] - tau);
                float a1 = clamp01(row[j+1] - tau);
                a0 *= a0; a1 *= a1;
                row[j+0] = a0; row[j+1] = a1;
                s0 += a0; s1 += a1;
            }
            inv_sum = 1.0f / (s0 + s1);
        } else {
            // faithful general-alpha path (unused for this problem's alpha=1.5)
            const float inv = 1.0f / am1;
            float tau_m = tau_lo;
            float f_lo = -1.0f;
            #pragma unroll
            for (int j = 0; j < 64; ++j) f_lo += pgen(row[j] - tau_lo, inv);
            for (int it = 0; it < 30; ++it) {
                dm *= 0.5f;
                tau_m = tau_lo + dm;
                float f = -1.0f;
                #pragma unroll
                for (int j = 0; j < 64; ++j) f += pgen(row[j] - tau_m, inv);
                tau_lo = (f * f_lo >= 0.0f) ? tau_m : tau_lo;
            }
            float s = 0.0f;
            #pragma unroll
            for (int j = 0; j < 64; ++j) {
                const float pm = pgen(row[j] - tau_m, inv);
                row[j] = pm;
                s += pm;
            }
            inv_sum = 1.0f / s;
        }

        // av: res[h][lane] = inv_sum * sum_j p[j] * v[h][j]  via fp16 dot2
        half2v p2[32];
        #pragma unroll
        for (int ii = 0; ii < 32; ++ii) p2[ii] = pk(row[2 * ii], row[2 * ii + 1]);

        float acc[8];
        #pragma unroll
        for (int h = 0; h < 8; ++h) {
            float a0 = 0.0f, a1 = 0.0f;
            #pragma unroll
            for (int jc = 0; jc < 8; ++jc) {
                union { half8 h8; half2v h2[4]; } u;
                u.h8 = *(const half8*)&vT[t * TOKPAD + h * 32 + jc * 4];
                a0 = dot2(p2[jc * 4 + 0], u.h2[0], a0);
                a1 = dot2(p2[jc * 4 + 1], u.h2[1], a1);
                a0 = dot2(p2[jc * 4 + 2], u.h2[2], a0);
                a1 = dot2(p2[jc * 4 + 3], u.h2[3], a1);
            }
            acc[h] = a0 + a1;
        }
        // res -> LDS overlay of qT row t (wave-private row; same fp16 cast)
        #pragma unroll
        for (int h = 0; h < 8; ++h)
            resL[t * 520 + h * 64 + lane] = (__fp16)(acc[h] * inv_sum);
    }
    __syncthreads();   // all 16 tokens' res in LDS -> out phase

    // ---- out phase: waves 0-3 compute out col tiles w*16..w*16+15.
    if (w < 4) {
        floatx4 oacc = (floatx4){0.f, 0.f, 0.f, 0.f};
        const __fp16* rrow = resL + (size_t)m * 520 + quad * 8;   // token m
        const __fp16* wrow = wuh + (size_t)(w * 16 + m) * HHE + quad * 8;
        #pragma unroll
        for (int kc = 0; kc < 16; ++kc) {              // K=512 in 32-chunks
            const half8 bf = *(const half8*)(rrow + kc * 32);
            const half8 af = *(const half8*)(wrow + kc * 32);
            oacc = __builtin_amdgcn_mfma_f32_16x16x32_f16(af, bf, oacc, 0, 0, 0);
        }
        const int tok = tok0 + m;
        const int col = w * 16 + quad * 4;             // 4 consecutive out cols
        const float4 b4 = *(const float4*)&bu[col];
        float4 o;
        o.x = oacc[0] + b4.x;
        o.y = oacc[1] + b4.y;
        o.z = oacc[2] + b4.z;
        o.w = oacc[3] + b4.w;
        *(float4*)&out[(size_t)tok * 64 + col] = o;
    }
}

// ---------------------------------------------------------------------------
extern "C" void kernel_launch(void* const* d_in, const int* in_sizes, int n_in,
                              void* d_out, int out_size, void* d_ws, size_t ws_size,
                              hipStream_t stream)
{
    const float* x     = (const float*)d_in[0];
    const float* alpha = (const float*)d_in[1];
    const float* Wk    = (const float*)d_in[2];
    const float* bk    = (const float*)d_in[3];
    const float* Wq    = (const float*)d_in[4];
    const float* bq    = (const float*)d_in[5];
    const float* Wv    = (const float*)d_in[6];
    const float* bv    = (const float*)d_in[7];
    const float* Wu    = (const float*)d_in[8];
    const float* bu    = (const float*)d_in[9];
    float* out = (float*)d_out;

    // workspace (fp16 units): xh 1M | wkh/wqh/wvh/wuh 32768 each
    __fp16* xh   = (__fp16*)d_ws;
    __fp16* wkh  = xh  + (size_t)NTOK * EDIM;
    __fp16* wqh  = wkh + (size_t)HHE * EDIM;
    __fp16* wvh  = wqh + (size_t)HHE * EDIM;
    __fp16* wuh  = wvh + (size_t)HHE * EDIM;

    cvt_fp16_kernel<<<dim3(512, 5), 256, 0, stream>>>(
        x, Wk, Wq, Wv, Wu, xh, wkh, wqh, wvh, wuh);
    qkv_attn_out_kernel<<<NTOK / 16, 512, 0, stream>>>(
        xh, wkh, bk, wqh, bq, wvh, bv, wuh, bu, out, alpha);
}

// Round 22
// 157.194 us; speedup vs baseline: 1.5716x; 1.0969x over previous
//
#include <hip/hip_runtime.h>
#include <math.h>

// Problem constants (b=8, c=2048, e=64, h=8)
#define NTOK 16384
#define EDIM 64
#define HHE  512   // h*e
#define TOKPAD 260 // half2 slots per token row: 256 + 4 pad (16B-aligned rows)

typedef _Float16 half8 __attribute__((ext_vector_type(8)));   // MFMA operand type
typedef __fp16   half2v __attribute__((ext_vector_type(2)));  // builtin V2h type
typedef float    floatx4 __attribute__((ext_vector_type(4)));

__device__ __forceinline__ half8 cvt8(const float4 a, const float4 b) {
    half8 h;
    h[0] = (_Float16)a.x; h[1] = (_Float16)a.y;
    h[2] = (_Float16)a.z; h[3] = (_Float16)a.w;
    h[4] = (_Float16)b.x; h[5] = (_Float16)b.y;
    h[6] = (_Float16)b.z; h[7] = (_Float16)b.w;
    return h;
}

// fp32 += half2 . half2 (v_dot2_f32_f16); float fallback if builtin missing
__device__ __forceinline__ float dot2(half2v a, half2v b, float c) {
#if __has_builtin(__builtin_amdgcn_fdot2)
    return __builtin_amdgcn_fdot2(a, b, c, false);
#else
    return fmaf((float)a[0], (float)b[0], fmaf((float)a[1], (float)b[1], c));
#endif
}
__device__ __forceinline__ half2v pk(float x, float y) {
    return __builtin_amdgcn_cvt_pkrtz(x, y);   // v_cvt_pkrtz_f16_f32 (V2h)
}
union h2u { half2v h; unsigned int u; };

__device__ __forceinline__ float clamp01(float z) {
    return __builtin_amdgcn_fmed3f(z, 0.0f, 1.0f);   // v_med3_f32
}
__device__ __forceinline__ float pgen(float z, float inv) {
    return z > 0.0f ? exp2f(inv * log2f(fmaxf(z, 1e-30f))) : 0.0f;
}

// ---------------------------------------------------------------------------
// Kernel 0: one-shot fp32 -> fp16 (RTN cast) for x + all W. (R16, unchanged)
// ---------------------------------------------------------------------------
__global__ __launch_bounds__(256) void cvt_fp16_kernel(
    const float* __restrict__ x,
    const float* __restrict__ Wk, const float* __restrict__ Wq,
    const float* __restrict__ Wv, const float* __restrict__ Wu,
    __fp16* __restrict__ xh, __fp16* __restrict__ wkh,
    __fp16* __restrict__ wqh, __fp16* __restrict__ wvh,
    __fp16* __restrict__ wuh)
{
    const int z = blockIdx.y;
    const float* src; __fp16* dst; int n;
    if      (z == 0) { src = x;  dst = xh;  n = NTOK * EDIM; }
    else if (z == 1) { src = Wk; dst = wkh; n = HHE * EDIM; }
    else if (z == 2) { src = Wq; dst = wqh; n = HHE * EDIM; }
    else if (z == 3) { src = Wv; dst = wvh; n = HHE * EDIM; }
    else             { src = Wu; dst = wuh; n = EDIM * HHE; }
    const int idx = (blockIdx.x * 256 + threadIdx.x) * 8;
    if (idx < n) {
        const float4 a = *(const float4*)(src + idx);
        const float4 b = *(const float4*)(src + idx + 4);
        *(half8*)(dst + idx) = cvt8(a, b);
    }
}

// ---------------------------------------------------------------------------
// Kernel 1: FULLY FUSED qkv + entmax-attention + output projection.
// R19 FINAL (best measured: 155.5 µs total). Block = 16 tokens, 4 waves.
// R20/R21 falsified the 8-wave variant (1 resident block/CU, VALUBusy 40%);
// R15 falsified smaller-LDS; R17 falsified packed-fp16 f-eval (VGPR up,
// occupancy down). This 4-wave shape is the converged structure.
//  - consumer writes token t's res (fp16) into qT row t's BYTES (qT is dead
//    after that wave's one dot-load of row t; rows t = w*4+i are wave-
//    private for both the q-read and the res-write -> no cross-wave hazard).
//  - after one barrier, wave w runs one 16-col tile of the out-MFMA
//    (af = Wu half8, bf = res half8 from LDS).
// ---------------------------------------------------------------------------
__global__ __launch_bounds__(256) void qkv_attn_out_kernel(
    const __fp16* __restrict__ xh,
    const __fp16* __restrict__ wkh, const float* __restrict__ bk,
    const __fp16* __restrict__ wqh, const float* __restrict__ bq,
    const __fp16* __restrict__ wvh, const float* __restrict__ bv,
    const __fp16* __restrict__ wuh, const float* __restrict__ bu,
    float* __restrict__ out, const float* alpha_p)
{
    __shared__ __align__(16) half2v qT[16 * TOKPAD];  // [tok][i*4+hpair] -> res overlay
    __shared__ __align__(16) half2v kT[16 * TOKPAD];  // [tok][j*4 + hpair]
    __shared__ __align__(16) half2v vT[16 * TOKPAD];  // [tok][h*32 + jpair]

    const int tid  = threadIdx.x;
    const int lane = tid & 63;
    const int w    = tid >> 6;
    const int tok0 = blockIdx.x * 16;

    const int m    = lane & 15;            // token (B row)
    const int quad = lane >> 4;

    // ---- x B-fragments (direct fp16), shared by this wave's 3 units
    const __fp16* xrow = xh + (size_t)(tok0 + m) * EDIM + quad * 8;
    half8 bfr[2];
    bfr[0] = *(const half8*)(xrow);
    bfr[1] = *(const half8*)(xrow + 32);

    // ---- producer: units w*3 .. w*3+2; unit = z*4 + ntile
    #pragma unroll
    for (int uu = 0; uu < 3; ++uu) {
        const int unit = w * 3 + uu;
        const int z    = unit >> 2;            // 0=k, 1=q, 2=v
        const int col0 = (unit & 3) * 128;
        const __fp16* W   = (z == 0) ? wkh : (z == 1) ? wqh : wvh;
        const float* bias = (z == 0) ? bk : (z == 1) ? bq : bv;
        half2v* dstT      = (z == 0) ? kT : (z == 1) ? qT : vT;

        #pragma unroll
        for (int ct = 0; ct < 8; ++ct) {
            const int n = col0 + ct * 16 + m;
            // permuted W row for q/k; natural for v
            const int grow = (z < 2) ? ((n & 7) * 64 + (n >> 3)) : n;
            const __fp16* wrow = W + (size_t)grow * EDIM + quad * 8;
            floatx4 acc = (floatx4){0.f, 0.f, 0.f, 0.f};
            #pragma unroll
            for (int kc = 0; kc < 2; ++kc) {
                const half8 af = *(const half8*)(wrow + kc * 32);  // direct fp16
                acc = __builtin_amdgcn_mfma_f32_16x16x32_f16(af, bfr[kc], acc, 0, 0, 0);
            }
            // lane's 4 regs = D rows quad*4+0..3, D col = m (token)
            h2u p0, p1;
            if (z < 2) {
                // output rows g(n'): h = 4*(quad&1)+reg, j = col0/8+ct*2+(quad>>1)
                const int hbase = 4 * (quad & 1);
                const int j     = (col0 >> 3) + ct * 2 + (quad >> 1);
                float o0 = acc[0] + bias[(hbase + 0) * 64 + j];
                float o1 = acc[1] + bias[(hbase + 1) * 64 + j];
                float o2 = acc[2] + bias[(hbase + 2) * 64 + j];
                float o3 = acc[3] + bias[(hbase + 3) * 64 + j];
                p0.h = pk(o0, o1);                 // h-pair 2*(quad&1)
                p1.h = pk(o2, o3);                 // h-pair 2*(quad&1)+1
                uint2 st; st.x = p0.u; st.y = p1.u;
                *(uint2*)&dstT[m * TOKPAD + j * 4 + 2 * (quad & 1)] = st;
            } else {
                // natural: cols nn..nn+3 = v[h][jj..jj+3]
                const int nn = col0 + ct * 16 + quad * 4;
                const int h  = nn >> 6;
                const int jj = nn & 63;
                const float4 b4 = *(const float4*)&bias[nn];
                p0.h = pk(acc[0] + b4.x, acc[1] + b4.y);
                p1.h = pk(acc[2] + b4.z, acc[3] + b4.w);
                uint2 st; st.x = p0.u; st.y = p1.u;
                *(uint2*)&dstT[m * TOKPAD + h * 32 + (jj >> 1)] = st;
            }
        }
    }
    __syncthreads();   // producer (all waves write all 16 tokens) -> consumer

    const float alpha = alpha_p[0];
    const float am1   = alpha - 1.0f;
    __fp16* resL = (__fp16*)qT;            // res overlay: row stride 520 halves

    // ---- consumer: each wave runs 4 tokens serially
    for (int i = 0; i < 4; ++i) {
        const int t = w * 4 + i;

        union { half8 h8; half2v h2[4]; } uq;
        uq.h8 = *(const half8*)&qT[t * TOKPAD + lane * 4];  // qT row t dead after this

        // dot row: row[j] = sum_h q[h][lane] * k[h][j]  (4 dot2 per j)
        float row[64];
        #pragma unroll
        for (int j = 0; j < 64; ++j) {
            union { half8 h8; half2v h2[4]; } u;
            u.h8 = *(const half8*)&kT[t * TOKPAD + j * 4];   // broadcast b128
            float d = dot2(uq.h2[0], u.h2[0], 0.0f);
            d = dot2(uq.h2[1], u.h2[1], d);
            d = dot2(uq.h2[2], u.h2[2], d);
            d = dot2(uq.h2[3], u.h2[3], d);
            row[j] = d;
        }

        // Xa = dot/sqrt(e) * (alpha-1);  1/8 and am1 fold exactly (pow-of-2)
        const float scale = am1 * 0.125f;
        #pragma unroll
        for (int j = 0; j < 64; ++j) row[j] *= scale;

        float mx = row[0];
        #pragma unroll
        for (int j = 1; j < 64; ++j) mx = fmaxf(mx, row[j]);

        float tau_lo = mx - 1.0f;                         // _gp(1, alpha) = 1
        const float tau_hi = mx - exp2f(-6.0f * am1);     // (1/64)^am1
        float dm = tau_hi - tau_lo;
        float inv_sum;

        if (am1 == 0.5f) {
            // 6 bisection steps, f >= 0 test (f_lo >= 0 provably; one-hot-safe)
            #pragma unroll
            for (int it = 0; it < 6; ++it) {
                dm *= 0.5f;
                const float tau_m = tau_lo + dm;
                float f0 = -1.0f, f1 = 0.0f, f2 = 0.0f, f3 = 0.0f;
                #pragma unroll
                for (int j = 0; j < 64; j += 4) {
                    const float a0 = clamp01(row[j+0] - tau_m);
                    const float a1 = clamp01(row[j+1] - tau_m);
                    const float a2 = clamp01(row[j+2] - tau_m);
                    const float a3 = clamp01(row[j+3] - tau_m);
                    f0 = fmaf(a0, a0, f0); f1 = fmaf(a1, a1, f1);
                    f2 = fmaf(a2, a2, f2); f3 = fmaf(a3, a3, f3);
                }
                const float f = (f0 + f1) + (f2 + f3);
                tau_lo = (f >= 0.0f) ? tau_m : tau_lo;
            }
            // 2 guarded Newton steps (tau += max(f,0)/(2s); never moves if f<0)
            float tau = tau_lo;
            #pragma unroll
            for (int it = 0; it < 2; ++it) {
                float f0 = -1.0f, f1 = 0.0f, f2 = 0.0f, f3 = 0.0f;
                float s0 = 0.0f, s1 = 0.0f, s2 = 0.0f, s3 = 0.0f;
                #pragma unroll
                for (int j = 0; j < 64; j += 4) {
                    const float a0 = clamp01(row[j+0] - tau);
                    const float a1 = clamp01(row[j+1] - tau);
                    const float a2 = clamp01(row[j+2] - tau);
                    const float a3 = clamp01(row[j+3] - tau);
                    f0 = fmaf(a0, a0, f0); f1 = fmaf(a1, a1, f1);
                    f2 = fmaf(a2, a2, f2); f3 = fmaf(a3, a3, f3);
                    s0 += a0; s1 += a1; s2 += a2; s3 += a3;
                }
                const float f = (f0 + f1) + (f2 + f3);
                const float s = ((s0 + s1) + (s2 + s3)) + 1e-20f;  // s >= 1/8
                tau = tau + fmaxf(f, 0.0f) / (s + s);
            }
            // final p (unnormalized) + sum; normalization folded into av
            float s0 = 0.0f, s1 = 0.0f;
            #pragma unroll
            for (int j = 0; j < 64; j += 2) {
                float a0 = clamp01(row[j+0] - tau);
                float a1 = clamp01(row[j+1] - tau);
                a0 *= a0; a1 *= a1;
                row[j+0] = a0; row[j+1] = a1;
                s0 += a0; s1 += a1;
            }
            inv_sum = 1.0f / (s0 + s1);
        } else {
            // faithful general-alpha path (unused for this problem's alpha=1.5)
            const float inv = 1.0f / am1;
            float tau_m = tau_lo;
            float f_lo = -1.0f;
            #pragma unroll
            for (int j = 0; j < 64; ++j) f_lo += pgen(row[j] - tau_lo, inv);
            for (int it = 0; it < 30; ++it) {
                dm *= 0.5f;
                tau_m = tau_lo + dm;
                float f = -1.0f;
                #pragma unroll
                for (int j = 0; j < 64; ++j) f += pgen(row[j] - tau_m, inv);
                tau_lo = (f * f_lo >= 0.0f) ? tau_m : tau_lo;
            }
            float s = 0.0f;
            #pragma unroll
            for (int j = 0; j < 64; ++j) {
                const float pm = pgen(row[j] - tau_m, inv);
                row[j] = pm;
                s += pm;
            }
            inv_sum = 1.0f / s;
        }

        // av: res[h][lane] = inv_sum * sum_j p[j] * v[h][j]  via fp16 dot2
        half2v p2[32];
        #pragma unroll
        for (int ii = 0; ii < 32; ++ii) p2[ii] = pk(row[2 * ii], row[2 * ii + 1]);

        float acc[8];
        #pragma unroll
        for (int h = 0; h < 8; ++h) {
            float a0 = 0.0f, a1 = 0.0f;
            #pragma unroll
            for (int jc = 0; jc < 8; ++jc) {
                union { half8 h8; half2v h2[4]; } u;
                u.h8 = *(const half8*)&vT[t * TOKPAD + h * 32 + jc * 4];
                a0 = dot2(p2[jc * 4 + 0], u.h2[0], a0);
                a1 = dot2(p2[jc * 4 + 1], u.h2[1], a1);
                a0 = dot2(p2[jc * 4 + 2], u.h2[2], a0);
                a1 = dot2(p2[jc * 4 + 3], u.h2[3], a1);
            }
            acc[h] = a0 + a1;
        }
        // res -> LDS overlay of qT row t (wave-private row; same fp16 cast
        // as the R18 global store => identical values feed the out MFMA)
        #pragma unroll
        for (int h = 0; h < 8; ++h)
            resL[t * 520 + h * 64 + lane] = (__fp16)(acc[h] * inv_sum);
    }
    __syncthreads();   // all 16 tokens' res in LDS -> out phase

    // ---- out phase: wave w computes out cols w*16..w*16+15 for 16 tokens.
    {
        floatx4 oacc = (floatx4){0.f, 0.f, 0.f, 0.f};
        const __fp16* rrow = resL + (size_t)m * 520 + quad * 8;   // token m
        const __fp16* wrow = wuh + (size_t)(w * 16 + m) * HHE + quad * 8;
        #pragma unroll
        for (int kc = 0; kc < 16; ++kc) {              // K=512 in 32-chunks
            const half8 bf = *(const half8*)(rrow + kc * 32);
            const half8 af = *(const half8*)(wrow + kc * 32);
            oacc = __builtin_amdgcn_mfma_f32_16x16x32_f16(af, bf, oacc, 0, 0, 0);
        }
        const int tok = tok0 + m;
        const int col = w * 16 + quad * 4;             // 4 consecutive out cols
        const float4 b4 = *(const float4*)&bu[col];
        float4 o;
        o.x = oacc[0] + b4.x;
        o.y = oacc[1] + b4.y;
        o.z = oacc[2] + b4.z;
        o.w = oacc[3] + b4.w;
        *(float4*)&out[(size_t)tok * 64 + col] = o;
    }
}

// ---------------------------------------------------------------------------
extern "C" void kernel_launch(void* const* d_in, const int* in_sizes, int n_in,
                              void* d_out, int out_size, void* d_ws, size_t ws_size,
                              hipStream_t stream)
{
    const float* x     = (const float*)d_in[0];
    const float* alpha = (const float*)d_in[1];
    const float* Wk    = (const float*)d_in[2];
    const float* bk    = (const float*)d_in[3];
    const float* Wq    = (const float*)d_in[4];
    const float* bq    = (const float*)d_in[5];
    const float* Wv    = (const float*)d_in[6];
    const float* bv    = (const float*)d_in[7];
    const float* Wu    = (const float*)d_in[8];
    const float* bu    = (const float*)d_in[9];
    float* out = (float*)d_out;

    // workspace (fp16 units): xh 1M | wkh/wqh/wvh/wuh 32768 each
    __fp16* xh   = (__fp16*)d_ws;
    __fp16* wkh  = xh  + (size_t)NTOK * EDIM;
    __fp16* wqh  = wkh + (size_t)HHE * EDIM;
    __fp16* wvh  = wqh + (size_t)HHE * EDIM;
    __fp16* wuh  = wvh + (size_t)HHE * EDIM;

    cvt_fp16_kernel<<<dim3(512, 5), 256, 0, stream>>>(
        x, Wk, Wq, Wv, Wu, xh, wkh, wqh, wvh, wuh);
    qkv_attn_out_kernel<<<NTOK / 16, 256, 0, stream>>>(
        xh, wkh, bk, wqh, bq, wvh, bv, wuh, bu, out, alpha);
}